// Round 17
// baseline (73.325 us; speedup 1.0000x reference)
//
#include <hip/hip_runtime.h>
#include <hip/hip_bf16.h>

#define B_ROWS 8192
#define DIM 256
#define C_CLS 5994
#define N_CHUNK 188       // 6016 / 32
#define NSPL 8
#define NPACK 444         // 256 emb-tiles + 188 W-tiles
#define NGEMM 512         // 64 panels x 8 splits
#define NDAS 64           // das blocks appended to k_logits grid
#define NMERGE 384
#define H_HALF 4096
#define SCALE_F 30.0f
#define MAXL 30.0f
#define EXPC 43.2808512266689f   // 30*log2(e):  exp(30x-30) = exp2(EXPC*x - EXPC)

#if defined(__has_builtin)
#if __has_builtin(__builtin_amdgcn_exp2f)
#define EXP2(x) __builtin_amdgcn_exp2f(x)
#endif
#endif
#ifndef EXP2
#define EXP2(x) exp2f(x)
#endif

typedef float f32x16 __attribute__((ext_vector_type(16)));
typedef long long ll;
typedef ll ll2 __attribute__((ext_vector_type(2)));

// ---------------- pack: norms + blocked FP8 layouts + accum zero ---------
// FP8 blocked layout per 32-row tile (8 KB), PAIRED frags so loads stay 16B:
// pair j (=frags 2j,2j+1): byte = j*1024 + h*512 + row*16 + slot*8 + idx.
// A wave's paired-frag load is lane-linear -> one contiguous 1 KB load.
__global__ __launch_bounds__(256)
void k_pack(const float* __restrict__ emb, const float* __restrict__ W,
            char* __restrict__ en_blk, char* __restrict__ wn_blk,
            float* __restrict__ accum) {
  __shared__ float ssm[256];
  __shared__ float rnl[32];
  const int b = blockIdx.x;
  const int t = threadIdx.x;
  if (b == 0 && t < 8) accum[t] = 0.f;   // accum[0..3] + counter(+pad), zeroed every call
  const bool isW = b >= (B_ROWS/32);
  const int tile = isW ? b - (B_ROWS/32) : b;
  const int l31 = t & 31;
  const int row = tile*32 + l31;
  const float* __restrict__ src = isW ? W : emb;
  const bool rv = (!isW) || (row < C_CLS);

  float v[4][8];
  float ss = 0.f;
  #pragma unroll
  for (int i=0;i<4;i++) {
    const int d0 = ((t>>6) + i*4)*16 + ((t>>5)&1)*8;
    if (rv) {
      float4 x0 = *(const float4*)(src + (size_t)row*DIM + d0);
      float4 x1 = *(const float4*)(src + (size_t)row*DIM + d0 + 4);
      v[i][0]=x0.x; v[i][1]=x0.y; v[i][2]=x0.z; v[i][3]=x0.w;
      v[i][4]=x1.x; v[i][5]=x1.y; v[i][6]=x1.z; v[i][7]=x1.w;
      ss += x0.x*x0.x + x0.y*x0.y + x0.z*x0.z + x0.w*x0.w
          + x1.x*x1.x + x1.y*x1.y + x1.z*x1.z + x1.w*x1.w;
    } else {
      #pragma unroll
      for (int j=0;j<8;j++) v[i][j] = 0.f;
    }
  }
  ssm[t] = ss;
  __syncthreads();
  if (t < 32) {
    float s = 0.f;
    #pragma unroll
    for (int j=0;j<8;j++) s += ssm[t + j*32];
    rnl[t] = 1.0f/(sqrtf(s) + 1e-12f);
  }
  __syncthreads();
  const float rn = rnl[l31];
  char* __restrict__ dst = (isW ? wn_blk : en_blk) + (size_t)tile*8192;
  #pragma unroll
  for (int i=0;i<4;i++) {
    const int kk = (t>>6) + i*4;
    const int off = (kk>>1)*1024 + ((t>>5)&1)*512 + l31*16 + (kk&1)*8;
    int d0 = 0, d1 = 0;
    d0 = __builtin_amdgcn_cvt_pk_fp8_f32(v[i][0]*rn, v[i][1]*rn, d0, false);
    d0 = __builtin_amdgcn_cvt_pk_fp8_f32(v[i][2]*rn, v[i][3]*rn, d0, true);
    d1 = __builtin_amdgcn_cvt_pk_fp8_f32(v[i][4]*rn, v[i][5]*rn, d1, false);
    d1 = __builtin_amdgcn_cvt_pk_fp8_f32(v[i][6]*rn, v[i][7]*rn, d1, true);
    uint2 u; u.x = (unsigned)d0; u.y = (unsigned)d1;
    *(uint2*)(dst + off) = u;
  }
}

// ---------------- main fused GEMM + stats (FP8), das piggy-backed --------
// blocks [0,NGEMM): GEMM, 64 panels x 8 splits, 4 waves x 32-row tile.
// blocks [NGEMM,NGEMM+NDAS): das pair distances (emb-only), fills CU drain.
// GEMM: barrier-free; B register-double-buffered; TWO independent MFMA
// accumulator chains (k-halves) interleaved 1:1 -> dep-chain stall halved.
__global__ __launch_bounds__(256, 2)
void k_logits(const char* __restrict__ en_blk, const char* __restrict__ wn_blk,
              const float* __restrict__ emb, const int* __restrict__ y_d,
              float* __restrict__ psum, unsigned* __restrict__ pkey,
              float* __restrict__ accum) {
  const int b = blockIdx.x;
  const int wid  = threadIdx.x >> 6;
  const int lane = threadIdx.x & 63;

  if (b >= NGEMM) {
    // ----- das: contrastive pair distances (f32, from raw emb) -----
    __shared__ float s0[4], s1[4];
    const int bd = b - NGEMM;
    float a2 = 0.f, a3 = 0.f;
    for (int i = bd*4 + wid; i < H_HALF; i += NDAS*4) {
      const int j = (i+1) & (H_HALF-1);
      const int di = y_d[i], dj = y_d[j], dih = y_d[i + H_HALF];
      float4 z = {0.f,0.f,0.f,0.f};
      float4 mi = (di==0)  ? *(const float4*)(emb + (size_t)i*DIM + lane*4) : z;
      float4 mj = (dj==0)  ? *(const float4*)(emb + (size_t)j*DIM + lane*4) : z;
      float4 ti = (dih!=0) ? *(const float4*)(emb + (size_t)(i+H_HALF)*DIM + lane*4)
                           : ((di!=0) ? *(const float4*)(emb + (size_t)i*DIM + lane*4) : z);
      float px = mi.x-mj.x, py = mi.y-mj.y, pz = mi.z-mj.z, pw = mi.w-mj.w;
      float nx = mi.x-ti.x, ny = mi.y-ti.y, nz = mi.z-ti.z, nw = mi.w-ti.w;
      float sp = px*px+py*py+pz*pz+pw*pw;
      float sn = nx*nx+ny*ny+nz*nz+nw*nw;
      #pragma unroll
      for (int off=1; off<64; off<<=1) { sp += __shfl_xor(sp, off); sn += __shfl_xor(sn, off); }
      if (lane == 0) {
        float dp = sqrtf(sp), dn = sqrtf(sn);
        float m = fmaxf(2.0f - dp, 0.f);
        a2 += m*m + dn*dn;
        a3 += dp + dn;
      }
    }
    if (lane == 0) { s0[wid] = a2; s1[wid] = a3; }
    __syncthreads();
    if (threadIdx.x == 0) {
      atomicAdd(&accum[2], s0[0]+s0[1]+s0[2]+s0[3]);
      atomicAdd(&accum[3], s1[0]+s1[1]+s1[2]+s1[3]);
    }
    return;
  }

  // ----- GEMM -----
  const int split = b & (NSPL-1);
  const int panel = b / NSPL;
  const int l31  = lane & 31;
  const int tile = panel*4 + wid;

  // A paired-frags: 8 contiguous 1 KB wave-loads, resident all loop
  ll2 a[8];
  const char* ab = en_blk + (size_t)tile*8192 + lane*16;
  #pragma unroll
  for (int j=0;j<8;j++) a[j] = *(const ll2*)(ab + j*1024);

  float ssum[16]; unsigned key[16];
  #pragma unroll
  for (int r=0;r<16;r++){ ssum[r]=0.f; key[r]=0u; }

  const int nit = (N_CHUNK - split + NSPL - 1) / NSPL;   // 24 or 23
  const char* p = wn_blk + (size_t)split*8192 + lane*16;
  const ptrdiff_t STEP = (ptrdiff_t)NSPL*8192;

  ll2 b0[4], b1[4];
  #pragma unroll
  for (int j=0;j<4;j++) b0[j] = *(const ll2*)(p + j*1024);
  #pragma unroll
  for (int j=0;j<4;j++) b1[j] = *(const ll2*)(p + (j+4)*1024);

  unsigned colu = (unsigned)(split*32 + l31);
  for (int it = 0; it < nit-1; ++it) {
    const char* pn = p + STEP;
    f32x16 acc0 = {}, acc1 = {};   // independent chains: k-lo / k-hi
    #pragma unroll
    for (int j=0;j<4;j++) {
      acc0 = __builtin_amdgcn_mfma_f32_32x32x16_fp8_fp8(a[j][0],   b0[j][0], acc0, 0,0,0);
      acc1 = __builtin_amdgcn_mfma_f32_32x32x16_fp8_fp8(a[j+4][0], b1[j][0], acc1, 0,0,0);
      acc0 = __builtin_amdgcn_mfma_f32_32x32x16_fp8_fp8(a[j][1],   b0[j][1], acc0, 0,0,0);
      acc1 = __builtin_amdgcn_mfma_f32_32x32x16_fp8_fp8(a[j+4][1], b1[j][1], acc1, 0,0,0);
    }
    #pragma unroll
    for (int j=0;j<4;j++) b0[j] = *(const ll2*)(pn + j*1024);
    #pragma unroll
    for (int j=0;j<4;j++) b1[j] = *(const ll2*)(pn + (j+4)*1024);
    // epilogue: pad cols are zero rows -> x~0 -> exp2(-43.3)~1e-13, negligible
    #pragma unroll
    for (int r=0;r<16;r++) {
      float x = acc0[r] + acc1[r];            // cosine in [-1,1] (+fp8 noise)
      ssum[r] += EXP2(fmaf(x, EXPC, -EXPC));
      unsigned ky = (__float_as_uint(x + 2.0f) & 0xFFFFE000u) | colu;  // x+2>0: monotone
      key[r] = ky > key[r] ? ky : key[r];
    }
    colu += NSPL*32;
    p = pn;
  }
  { // last chunk, no prefetch
    f32x16 acc0 = {}, acc1 = {};
    #pragma unroll
    for (int j=0;j<4;j++) {
      acc0 = __builtin_amdgcn_mfma_f32_32x32x16_fp8_fp8(a[j][0],   b0[j][0], acc0, 0,0,0);
      acc1 = __builtin_amdgcn_mfma_f32_32x32x16_fp8_fp8(a[j+4][0], b1[j][0], acc1, 0,0,0);
      acc0 = __builtin_amdgcn_mfma_f32_32x32x16_fp8_fp8(a[j][1],   b0[j][1], acc0, 0,0,0);
      acc1 = __builtin_amdgcn_mfma_f32_32x32x16_fp8_fp8(a[j+4][1], b1[j][1], acc1, 0,0,0);
    }
    #pragma unroll
    for (int r=0;r<16;r++) {
      float x = acc0[r] + acc1[r];
      ssum[r] += EXP2(fmaf(x, EXPC, -EXPC));
      unsigned ky = (__float_as_uint(x + 2.0f) & 0xFFFFE000u) | colu;
      key[r] = ky > key[r] ? ky : key[r];
    }
  }

  // reduce across the 32 lanes (cols)
  #pragma unroll
  for (int off=1; off<32; off<<=1) {
    #pragma unroll
    for (int r=0;r<16;r++) {
      ssum[r] += __shfl_xor(ssum[r], off);
      unsigned o = __shfl_xor(key[r], off);
      key[r] = o > key[r] ? o : key[r];
    }
  }
  if (l31 == 0) {
    const int rowbase = tile*32;
    #pragma unroll
    for (int r=0;r<16;r++) {
      int row = rowbase + (r&3) + 8*(r>>2) + 4*(lane>>5);
      psum[split*B_ROWS + row] = ssum[r];
      pkey[split*B_ROWS + row] = key[r];
    }
  }
}

// ---------------- tail: merge only + finalize (completion counter) -------
__global__ __launch_bounds__(256)
void k_tail(const float* __restrict__ emb, const float* __restrict__ W,
            const int* __restrict__ y,
            const float* __restrict__ psum, const unsigned* __restrict__ pkey,
            float* __restrict__ accum, float* __restrict__ out) {
  __shared__ float s0[4], s1[4];
  const int wid = threadIdx.x >> 6, lane = threadIdx.x & 63;
  // ----- merge: per-row exact y-logit (f32 from emb/W) + partials -----
  float lacc = 0.f, cacc = 0.f;
  for (int row = blockIdx.x*4 + wid; row < B_ROWS; row += NMERGE*4) {
    const int yc = y[row];
    float4 e = *(const float4*)(emb + (size_t)row*DIM + lane*4);
    float4 w = *(const float4*)(W + (size_t)yc*DIM + lane*4);
    float d = e.x*w.x + e.y*w.y + e.z*w.z + e.w*w.w;
    float e2 = e.x*e.x + e.y*e.y + e.z*e.z + e.w*e.w;
    float w2 = w.x*w.x + w.y*w.y + w.z*w.z + w.w*w.w;
    #pragma unroll
    for (int off=1; off<64; off<<=1) {
      d += __shfl_xor(d, off); e2 += __shfl_xor(e2, off); w2 += __shfl_xor(w2, off);
    }
    float S = 0.f; unsigned km = 0u;
    if (lane < NSPL) {
      S = psum[lane*B_ROWS + row];
      km = pkey[lane*B_ROWS + row];
    }
    #pragma unroll
    for (int off=1; off<NSPL; off<<=1) {
      S += __shfl_xor(S, off);
      unsigned o = __shfl_xor(km, off);
      if (o > km) km = o;
    }
    if (lane == 0) {
      float ly = SCALE_F * d / ((sqrtf(e2) + 1e-12f) * (sqrtf(w2) + 1e-12f));
      lacc += MAXL + logf(S) - ly;
      cacc += ((km & 0x1FFFu) == (unsigned)yc) ? 1.f : 0.f;
    }
  }
  if (lane == 0) { s0[wid] = lacc; s1[wid] = cacc; }
  __syncthreads();
  if (threadIdx.x == 0) {
    atomicAdd(&accum[0], s0[0]+s0[1]+s0[2]+s0[3]);
    atomicAdd(&accum[1], s1[0]+s1[1]+s1[2]+s1[3]);
  }
  // ----- finalize: last block to finish writes the 4 outputs -----
  if (threadIdx.x == 0) {
    __threadfence();                                   // publish accum adds
    unsigned* cnt = (unsigned*)(accum + 4);
    unsigned done = atomicAdd(cnt, 1u);
    if (done == NMERGE-1u) {                           // last merge block
      float v0 = atomicAdd(&accum[0], 0.f);            // coherent reads
      float v1 = atomicAdd(&accum[1], 0.f);
      float v2 = atomicAdd(&accum[2], 0.f);            // das (from k_logits)
      float v3 = atomicAdd(&accum[3], 0.f);
      out[0] = v0 * (1.0f/B_ROWS);  // loss_c
      out[1] = v2 * (1.0f/B_ROWS);  // das_loss
      out[2] = v1 * (1.0f/B_ROWS);  // acc
      out[3] = v3 * (1.0f/B_ROWS);  // das_dist_mean
    }
  }
}

extern "C" void kernel_launch(void* const* d_in, const int* in_sizes, int n_in,
                              void* d_out, int out_size, void* d_ws, size_t ws_size,
                              hipStream_t stream) {
  const float* emb = (const float*)d_in[0];
  const float* W   = (const float*)d_in[1];
  const int*   y   = (const int*)d_in[2];
  const int*   y_d = (const int*)d_in[3];

  char* ws = (char*)d_ws;
  const size_t EN_OFF   = 0;                                  // 256 tiles * 8 KB
  const size_t WN_OFF   = EN_OFF  + (size_t)256*8192;
  const size_t PSUM_OFF = WN_OFF  + (size_t)N_CHUNK*8192;
  const size_t PKEY_OFF = PSUM_OFF + (size_t)NSPL*B_ROWS*4;   // 8*8192*4
  const size_t ACC_OFF  = PKEY_OFF + (size_t)NSPL*B_ROWS*4;   // 32 B (4 f32 + cnt + pad)

  char*     en_blk = ws + EN_OFF;
  char*     wn_blk = ws + WN_OFF;
  float*    psum  = (float*)(ws + PSUM_OFF);
  unsigned* pkey  = (unsigned*)(ws + PKEY_OFF);
  float*    accum = (float*)(ws + ACC_OFF);

  k_pack<<<NPACK, 256, 0, stream>>>(emb, W, en_blk, wn_blk, accum);
  k_logits<<<NGEMM + NDAS, 256, 0, stream>>>(en_blk, wn_blk, emb, y_d, psum, pkey, accum);
  k_tail<<<NMERGE, 256, 0, stream>>>(emb, W, y, psum, pkey, accum, (float*)d_out);
}

// Round 18
// 67.481 us; speedup vs baseline: 1.0866x; 1.0866x over previous
//
#include <hip/hip_runtime.h>
#include <hip/hip_bf16.h>

#define B_ROWS 8192
#define DIM 256
#define C_CLS 5994
#define N_CHUNK 188       // 6016 / 32
#define NSPL 8
#define NPACK 444         // 256 emb-tiles + 188 W-tiles
#define H_HALF 4096
#define SCALE_F 30.0f
#define MAXL 30.0f
#define EXPC 43.2808512266689f   // 30*log2(e):  exp(30x-30) = exp2(EXPC*x - EXPC)

#if defined(__has_builtin)
#if __has_builtin(__builtin_amdgcn_exp2f)
#define EXP2(x) __builtin_amdgcn_exp2f(x)
#endif
#endif
#ifndef EXP2
#define EXP2(x) exp2f(x)
#endif

typedef float f32x16 __attribute__((ext_vector_type(16)));
typedef long long ll;
typedef ll ll2 __attribute__((ext_vector_type(2)));

// ---------------- pack: norms + blocked FP8 layouts + accum zero ---------
// FP8 blocked layout per 32-row tile (8 KB), PAIRED frags:
//   pair j (=frags 2j,2j+1): byte = j*1024 + h*512 + row*16 + slot*8 + idx
//   -> thread handles one (row, j, h): d in {32j+8h+0..7} U {32j+8h+16..23},
//      writes ONE uint4 (16 consecutive bytes) -- fully coalesced stores.
__global__ __launch_bounds__(256)
void k_pack(const float* __restrict__ emb, const float* __restrict__ W,
            char* __restrict__ en_blk, char* __restrict__ wn_blk,
            float* __restrict__ accum) {
  __shared__ float ssm[256];
  __shared__ float rnl[32];
  const int b = blockIdx.x;
  const int t = threadIdx.x;
  if (b == 0 && t < 8) accum[t] = 0.f;   // accum[0..3] + counter(+pad), zeroed every call
  const bool isW = b >= (B_ROWS/32);
  const int tile = isW ? b - (B_ROWS/32) : b;
  const int row = t & 31;
  const int c   = t >> 5;                // combo 0..7; thread covers combos c and c+8
  const int grow = tile*32 + row;
  const float* __restrict__ src = isW ? W : emb;
  const bool rv = (!isW) || (grow < C_CLS);

  // two combos: cc = c, c+8;  j = cc>>1, h = cc&1;  base d0 = 32j + 8h
  float va[2][16];
  float ss = 0.f;
  #pragma unroll
  for (int q=0;q<2;q++) {
    const int cc = c + q*8;
    const int d0 = 32*(cc>>1) + 8*(cc&1);
    if (rv) {
      float4 x0 = *(const float4*)(src + (size_t)grow*DIM + d0);
      float4 x1 = *(const float4*)(src + (size_t)grow*DIM + d0 + 4);
      float4 x2 = *(const float4*)(src + (size_t)grow*DIM + d0 + 16);
      float4 x3 = *(const float4*)(src + (size_t)grow*DIM + d0 + 20);
      va[q][0]=x0.x; va[q][1]=x0.y; va[q][2]=x0.z; va[q][3]=x0.w;
      va[q][4]=x1.x; va[q][5]=x1.y; va[q][6]=x1.z; va[q][7]=x1.w;
      va[q][8]=x2.x; va[q][9]=x2.y; va[q][10]=x2.z; va[q][11]=x2.w;
      va[q][12]=x3.x; va[q][13]=x3.y; va[q][14]=x3.z; va[q][15]=x3.w;
      #pragma unroll
      for (int i=0;i<16;i++) ss += va[q][i]*va[q][i];
    } else {
      #pragma unroll
      for (int i=0;i<16;i++) va[q][i] = 0.f;
    }
  }
  ssm[t] = ss;
  __syncthreads();
  if (t < 32) {
    float s = 0.f;
    #pragma unroll
    for (int j=0;j<8;j++) s += ssm[t + j*32];
    rnl[t] = 1.0f/(sqrtf(s) + 1e-12f);
  }
  __syncthreads();
  const float rn = rnl[row];
  char* __restrict__ dst = (isW ? wn_blk : en_blk) + (size_t)tile*8192;
  #pragma unroll
  for (int q=0;q<2;q++) {
    const int cc = c + q*8;
    const int off = (cc>>1)*1024 + (cc&1)*512 + row*16;
    int w0=0, w1=0, w2=0, w3=0;
    w0 = __builtin_amdgcn_cvt_pk_fp8_f32(va[q][0]*rn,  va[q][1]*rn,  w0, false);
    w0 = __builtin_amdgcn_cvt_pk_fp8_f32(va[q][2]*rn,  va[q][3]*rn,  w0, true);
    w1 = __builtin_amdgcn_cvt_pk_fp8_f32(va[q][4]*rn,  va[q][5]*rn,  w1, false);
    w1 = __builtin_amdgcn_cvt_pk_fp8_f32(va[q][6]*rn,  va[q][7]*rn,  w1, true);
    w2 = __builtin_amdgcn_cvt_pk_fp8_f32(va[q][8]*rn,  va[q][9]*rn,  w2, false);
    w2 = __builtin_amdgcn_cvt_pk_fp8_f32(va[q][10]*rn, va[q][11]*rn, w2, true);
    w3 = __builtin_amdgcn_cvt_pk_fp8_f32(va[q][12]*rn, va[q][13]*rn, w3, false);
    w3 = __builtin_amdgcn_cvt_pk_fp8_f32(va[q][14]*rn, va[q][15]*rn, w3, true);
    uint4 u; u.x=(unsigned)w0; u.y=(unsigned)w1; u.z=(unsigned)w2; u.w=(unsigned)w3;
    *(uint4*)(dst + off) = u;            // one coalesced 16B store
  }
}

// ---------------- main fused GEMM + online softmax-stats (FP8) ----------
// grid = 64 panels x 8 splits = 512 blocks; block = 256 (4 waves).
// Barrier-free; B register-double-buffered; software-pipelined epilogue
// (chunk i's MFMAs issue, then chunk i-1's epilogue under the MFMA shadow).
// NOTE: b0-MFMA -> b0-prefetch -> b1-MFMA -> b1-prefetch ordering keeps only
// one half-buffer live at a time (keeps VGPR ~104, preserves pipelining).
__global__ __launch_bounds__(256, 2)
void k_logits(const char* __restrict__ en_blk, const char* __restrict__ wn_blk,
              float* __restrict__ psum, unsigned* __restrict__ pkey) {
  const int split = blockIdx.x & (NSPL-1);
  const int panel = blockIdx.x / NSPL;
  const int wid  = threadIdx.x >> 6;
  const int lane = threadIdx.x & 63;
  const int l31  = lane & 31;
  const int tile = panel*4 + wid;

  // A paired-frags: 8 contiguous 1 KB wave-loads, resident all loop
  ll2 a[8];
  const char* ab = en_blk + (size_t)tile*8192 + lane*16;
  #pragma unroll
  for (int j=0;j<8;j++) a[j] = *(const ll2*)(ab + j*1024);

  float ssum[16]; unsigned key[16];
  #pragma unroll
  for (int r=0;r<16;r++){ ssum[r]=0.f; key[r]=0u; }

  const int nit = (N_CHUNK - split + NSPL - 1) / NSPL;   // 24 or 23
  const char* p = wn_blk + (size_t)split*8192 + lane*16;
  const ptrdiff_t STEP = (ptrdiff_t)NSPL*8192;

  ll2 b0[4], b1[4];
  #pragma unroll
  for (int j=0;j<4;j++) b0[j] = *(const ll2*)(p + j*1024);
  #pragma unroll
  for (int j=0;j<4;j++) b1[j] = *(const ll2*)(p + (j+4)*1024);

  int c = split;
  f32x16 accA = {}, accB = {};
  unsigned cluA = 0, cluB = 0;

#define MFMA_CHUNK(ACC) do { \
    const char* pn_ = p + STEP; \
    const bool pf_ = (c + NSPL) < N_CHUNK; \
    _Pragma("unroll") \
    for (int j=0;j<4;j++) { \
      ACC = __builtin_amdgcn_mfma_f32_32x32x16_fp8_fp8(a[j][0], b0[j][0], ACC, 0,0,0); \
      ACC = __builtin_amdgcn_mfma_f32_32x32x16_fp8_fp8(a[j][1], b0[j][1], ACC, 0,0,0); \
    } \
    if (pf_) { _Pragma("unroll") for (int j=0;j<4;j++) b0[j] = *(const ll2*)(pn_ + j*1024); } \
    _Pragma("unroll") \
    for (int j=0;j<4;j++) { \
      ACC = __builtin_amdgcn_mfma_f32_32x32x16_fp8_fp8(a[j+4][0], b1[j][0], ACC, 0,0,0); \
      ACC = __builtin_amdgcn_mfma_f32_32x32x16_fp8_fp8(a[j+4][1], b1[j][1], ACC, 0,0,0); \
    } \
    if (pf_) { _Pragma("unroll") for (int j=0;j<4;j++) b1[j] = *(const ll2*)(pn_ + (j+4)*1024); } \
    p = pn_; c += NSPL; \
  } while (0)

#define EPI(ACC, CLU) do { \
    _Pragma("unroll") \
    for (int r=0;r<16;r++) { \
      float x_ = ACC[r];                        /* cosine in [-1,1] (+fp8 noise) */ \
      ssum[r] += EXP2(fmaf(x_, EXPC, -EXPC)); \
      unsigned ky_ = (__float_as_uint(x_ + 2.0f) & 0xFFFFE000u) | (CLU); \
      key[r] = ky_ > key[r] ? ky_ : key[r]; \
    } \
  } while (0)

  // prologue: chunk 0 MFMA only (epilogue lags one chunk)
  cluA = (unsigned)(c*32 + l31);
  MFMA_CHUNK(accA);
  for (int it = 1; it < nit; ++it) {
    if (it & 1) {
      cluB = (unsigned)(c*32 + l31);
      MFMA_CHUNK(accB);          // issue chunk-i MFMAs
      EPI(accA, cluA);           // epilogue chunk i-1 under MFMA shadow
      accA = (f32x16){};
    } else {
      cluA = (unsigned)(c*32 + l31);
      MFMA_CHUNK(accA);
      EPI(accB, cluB);
      accB = (f32x16){};
    }
  }
  if ((nit - 1) & 1) EPI(accB, cluB); else EPI(accA, cluA);
#undef MFMA_CHUNK
#undef EPI

  // reduce across the 32 lanes (cols)
  #pragma unroll
  for (int off=1; off<32; off<<=1) {
    #pragma unroll
    for (int r=0;r<16;r++) {
      ssum[r] += __shfl_xor(ssum[r], off);
      unsigned o = __shfl_xor(key[r], off);
      key[r] = o > key[r] ? o : key[r];
    }
  }
  if (l31 == 0) {
    const int rowbase = tile*32;
    #pragma unroll
    for (int r=0;r<16;r++) {
      int row = rowbase + (r&3) + 8*(r>>2) + 4*(lane>>5);
      psum[split*B_ROWS + row] = ssum[r];
      pkey[split*B_ROWS + row] = key[r];
    }
  }
}

// ---------------- tail: das + merge + finalize (completion counter) ------
__global__ __launch_bounds__(256)
void k_tail(const float* __restrict__ emb, const float* __restrict__ W,
            const int* __restrict__ y, const int* __restrict__ y_d,
            const float* __restrict__ psum, const unsigned* __restrict__ pkey,
            float* __restrict__ accum, float* __restrict__ out) {
  __shared__ float s0[4], s1[4];
  const int wid = threadIdx.x >> 6, lane = threadIdx.x & 63;
  if (blockIdx.x < 128) {
    // ----- merge: per-row exact y-logit (f32 from emb/W) + partials -----
    float lacc = 0.f, cacc = 0.f;
    for (int row = blockIdx.x*4 + wid; row < B_ROWS; row += 512) {
      const int yc = y[row];
      float4 e = *(const float4*)(emb + (size_t)row*DIM + lane*4);
      float4 w = *(const float4*)(W + (size_t)yc*DIM + lane*4);
      float d = e.x*w.x + e.y*w.y + e.z*w.z + e.w*w.w;
      float e2 = e.x*e.x + e.y*e.y + e.z*e.z + e.w*e.w;
      float w2 = w.x*w.x + w.y*w.y + w.z*w.z + w.w*w.w;
      #pragma unroll
      for (int off=1; off<64; off<<=1) {
        d += __shfl_xor(d, off); e2 += __shfl_xor(e2, off); w2 += __shfl_xor(w2, off);
      }
      float S = 0.f; unsigned km = 0u;
      if (lane < NSPL) {
        S = psum[lane*B_ROWS + row];
        km = pkey[lane*B_ROWS + row];
      }
      #pragma unroll
      for (int off=1; off<NSPL; off<<=1) {
        S += __shfl_xor(S, off);
        unsigned o = __shfl_xor(km, off);
        if (o > km) km = o;
      }
      if (lane == 0) {
        float ly = SCALE_F * d / ((sqrtf(e2) + 1e-12f) * (sqrtf(w2) + 1e-12f));
        lacc += MAXL + logf(S) - ly;
        cacc += ((km & 0x1FFFu) == (unsigned)yc) ? 1.f : 0.f;
      }
    }
    if (lane == 0) { s0[wid] = lacc; s1[wid] = cacc; }
    __syncthreads();
    if (threadIdx.x == 0) {
      atomicAdd(&accum[0], s0[0]+s0[1]+s0[2]+s0[3]);
      atomicAdd(&accum[1], s1[0]+s1[1]+s1[2]+s1[3]);
    }
  } else {
    // ----- das: contrastive pair distances (f32, from raw emb) -----
    float a2 = 0.f, a3 = 0.f;
    for (int i = (blockIdx.x-128)*4 + wid; i < H_HALF; i += 256) {
      const int j = (i+1) & (H_HALF-1);
      const int di = y_d[i], dj = y_d[j], dih = y_d[i + H_HALF];
      float4 z = {0.f,0.f,0.f,0.f};
      float4 mi = (di==0)  ? *(const float4*)(emb + (size_t)i*DIM + lane*4) : z;
      float4 mj = (dj==0)  ? *(const float4*)(emb + (size_t)j*DIM + lane*4) : z;
      float4 ti = (dih!=0) ? *(const float4*)(emb + (size_t)(i+H_HALF)*DIM + lane*4)
                           : ((di!=0) ? *(const float4*)(emb + (size_t)i*DIM + lane*4) : z);
      float px = mi.x-mj.x, py = mi.y-mj.y, pz = mi.z-mj.z, pw = mi.w-mj.w;
      float nx = mi.x-ti.x, ny = mi.y-ti.y, nz = mi.z-ti.z, nw = mi.w-ti.w;
      float sp = px*px+py*py+pz*pz+pw*pw;
      float sn = nx*nx+ny*ny+nz*nz+nw*nw;
      #pragma unroll
      for (int off=1; off<64; off<<=1) { sp += __shfl_xor(sp, off); sn += __shfl_xor(sn, off); }
      if (lane == 0) {
        float dp = sqrtf(sp), dn = sqrtf(sn);
        float m = fmaxf(2.0f - dp, 0.f);
        a2 += m*m + dn*dn;
        a3 += dp + dn;
      }
    }
    if (lane == 0) { s0[wid] = a2; s1[wid] = a3; }
    __syncthreads();
    if (threadIdx.x == 0) {
      atomicAdd(&accum[2], s0[0]+s0[1]+s0[2]+s0[3]);
      atomicAdd(&accum[3], s1[0]+s1[1]+s1[2]+s1[3]);
    }
  }
  // ----- finalize: last block to finish writes the 4 outputs -----
  if (threadIdx.x == 0) {
    __threadfence();                                   // publish accum adds
    unsigned* cnt = (unsigned*)(accum + 4);
    unsigned done = atomicAdd(cnt, 1u);
    if (done == 191u) {                                // last of 192 blocks
      float v0 = atomicAdd(&accum[0], 0.f);            // coherent reads
      float v1 = atomicAdd(&accum[1], 0.f);
      float v2 = atomicAdd(&accum[2], 0.f);
      float v3 = atomicAdd(&accum[3], 0.f);
      out[0] = v0 * (1.0f/B_ROWS);  // loss_c
      out[1] = v2 * (1.0f/B_ROWS);  // das_loss
      out[2] = v1 * (1.0f/B_ROWS);  // acc
      out[3] = v3 * (1.0f/B_ROWS);  // das_dist_mean
    }
  }
}

extern "C" void kernel_launch(void* const* d_in, const int* in_sizes, int n_in,
                              void* d_out, int out_size, void* d_ws, size_t ws_size,
                              hipStream_t stream) {
  const float* emb = (const float*)d_in[0];
  const float* W   = (const float*)d_in[1];
  const int*   y   = (const int*)d_in[2];
  const int*   y_d = (const int*)d_in[3];

  char* ws = (char*)d_ws;
  const size_t EN_OFF   = 0;                                  // 256 tiles * 8 KB
  const size_t WN_OFF   = EN_OFF  + (size_t)256*8192;
  const size_t PSUM_OFF = WN_OFF  + (size_t)N_CHUNK*8192;
  const size_t PKEY_OFF = PSUM_OFF + (size_t)NSPL*B_ROWS*4;   // 8*8192*4
  const size_t ACC_OFF  = PKEY_OFF + (size_t)NSPL*B_ROWS*4;   // 32 B (4 f32 + cnt + pad)

  char*     en_blk = ws + EN_OFF;
  char*     wn_blk = ws + WN_OFF;
  float*    psum  = (float*)(ws + PSUM_OFF);
  unsigned* pkey  = (unsigned*)(ws + PKEY_OFF);
  float*    accum = (float*)(ws + ACC_OFF);

  k_pack<<<NPACK, 256, 0, stream>>>(emb, W, en_blk, wn_blk, accum);
  k_logits<<<64*NSPL, 256, 0, stream>>>(en_blk, wn_blk, psum, pkey);
  k_tail<<<192, 256, 0, stream>>>(emb, W, y, y_d, psum, pkey, accum, (float*)d_out);
}